// Round 2
// baseline (234.649 us; speedup 1.0000x reference)
//
#include <hip/hip_runtime.h>
#include <hip/hip_bf16.h>

typedef float f32x4 __attribute__((ext_vector_type(4)));
typedef short s16x8 __attribute__((ext_vector_type(8)));
typedef unsigned short u16;

#define B_ 4
#define C_ 512
#define H_ 128
#define W_ 128
#define NO_ 640   // 64 q + 64 k + 512 v output channels

__device__ __forceinline__ u16 f2bf(float f) {
    __hip_bfloat16 h = __float2bfloat16(f);
    union { __hip_bfloat16 h; u16 u; } cv; cv.h = h; return cv.u;
}
__device__ __forceinline__ float bf2f(u16 u) {
    union { unsigned u; float f; } cv; cv.u = ((unsigned)u) << 16; return cv.f;
}

// async global->LDS, 16B per lane; LDS dest must be wave_base + lane*16 (it is: t*16 bytes)
__device__ __forceinline__ void gld16(const u16* g, u16* l) {
    __builtin_amdgcn_global_load_lds(
        (const __attribute__((address_space(1))) void*)g,
        (__attribute__((address_space(3))) void*)l, 16, 0, 0);
}

// ---------------------------------------------------------------- K0: weights
__global__ __launch_bounds__(256) void k_convw(const float* __restrict__ Wq, const float* __restrict__ bq,
                                               const float* __restrict__ Wk, const float* __restrict__ bk,
                                               const float* __restrict__ Wv, const float* __restrict__ bv,
                                               u16* __restrict__ Wcat, float* __restrict__ bcat) {
    const int idx = blockIdx.x * 256 + threadIdx.x;
    if (idx < NO_ * C_) {
        const int o = idx >> 9, c = idx & 511;
        float v;
        if (o < 64)       v = Wq[o * C_ + c];
        else if (o < 128) v = Wk[(o - 64) * C_ + c];
        else              v = Wv[(o - 128) * C_ + c];
        Wcat[idx] = f2bf(v);
    }
    if (idx < NO_) {
        float v = (idx < 64) ? bq[idx] : ((idx < 128) ? bk[idx - 64] : bv[idx - 128]);
        bcat[idx] = v;
    }
}

// ------------------------------------------------- K1: x[B,C,H,W] -> xT[b][w][h][c] bf16
__global__ __launch_bounds__(256) void k_transpose_x(const float* __restrict__ x, u16* __restrict__ xT) {
    __shared__ float tile[64][65];
    const int b  = blockIdx.x >> 7;
    const int h  = blockIdx.x & 127;
    const int c0 = (blockIdx.y >> 1) * 64;
    const int w0 = (blockIdx.y & 1) * 64;
    const int t = threadIdx.x, r = t >> 4, seg = t & 15;
    const float* xp = x + (size_t)b * C_ * H_ * W_ + (size_t)h * W_;
#pragma unroll
    for (int rr = 0; rr < 4; ++rr) {
        const int c = rr * 16 + r;
        float4 v = *(const float4*)(xp + (size_t)(c0 + c) * (H_ * W_) + w0 + seg * 4);
        tile[c][seg * 4 + 0] = v.x; tile[c][seg * 4 + 1] = v.y;
        tile[c][seg * 4 + 2] = v.z; tile[c][seg * 4 + 3] = v.w;
    }
    __syncthreads();
#pragma unroll
    for (int rr = 0; rr < 4; ++rr) {
        const int w = rr * 16 + r;
        ushort4 u;
        u.x = f2bf(tile[seg * 4 + 0][w]); u.y = f2bf(tile[seg * 4 + 1][w]);
        u.z = f2bf(tile[seg * 4 + 2][w]); u.w = f2bf(tile[seg * 4 + 3][w]);
        *(ushort4*)(xT + ((size_t)((b * W_ + w0 + w) * H_ + h)) * C_ + c0 + seg * 4) = u;
    }
}

// ------------------------------------------------- K2: Call[r][o] = xT[r][:] . Wcat[o][:] + b[o]
// m97 structure: 128x128 tile, BK=32, 4 waves (2x2), global_load_lds width-16 staging.
__global__ __launch_bounds__(256) void k_gemm(const u16* __restrict__ A, const u16* __restrict__ Wc,
                                              const float* __restrict__ bias, u16* __restrict__ Call) {
    __shared__ __align__(16) u16 As[128 * 32];
    __shared__ __align__(16) u16 Bs[128 * 32];
    const int t = threadIdx.x;
    const int lane = t & 63;
    const int wr = t >> 7;
    const int wc = (t >> 6) & 1;
    const int r0 = blockIdx.x * 128;
    const int n0 = blockIdx.y * 128;
    const int srow = t >> 2, sseg = (t & 3) * 8;
    const int lr = lane & 15, lk = (lane >> 4) * 8;
    const u16* pa0 = A  + (size_t)(r0 + srow) * C_ + sseg;
    const u16* pa1 = pa0 + (size_t)64 * C_;
    const u16* pb0 = Wc + (size_t)(n0 + srow) * C_ + sseg;
    const u16* pb1 = pb0 + (size_t)64 * C_;
    f32x4 acc[4][4] = {};
    for (int kk = 0; kk < C_; kk += 32) {
        gld16(pa0 + kk, &As[t * 8]);
        gld16(pa1 + kk, &As[2048 + t * 8]);
        gld16(pb0 + kk, &Bs[t * 8]);
        gld16(pb1 + kk, &Bs[2048 + t * 8]);
        __syncthreads();   // drains vmcnt -> LDS writes visible
        s16x8 fa[4], fb[4];
#pragma unroll
        for (int mi = 0; mi < 4; ++mi)
            fa[mi] = *(const s16x8*)&As[(wr * 64 + mi * 16 + lr) * 32 + lk];
#pragma unroll
        for (int ni = 0; ni < 4; ++ni)
            fb[ni] = *(const s16x8*)&Bs[(wc * 64 + ni * 16 + lr) * 32 + lk];
#pragma unroll
        for (int mi = 0; mi < 4; ++mi)
#pragma unroll
            for (int ni = 0; ni < 4; ++ni)
                acc[mi][ni] = __builtin_amdgcn_mfma_f32_16x16x32_bf16(fa[mi], fb[ni], acc[mi][ni], 0, 0, 0);
        __syncthreads();
    }
#pragma unroll
    for (int ni = 0; ni < 4; ++ni) {
        const int o = n0 + wc * 64 + ni * 16 + lr;
        const float bz = bias[o];
#pragma unroll
        for (int mi = 0; mi < 4; ++mi)
#pragma unroll
            for (int j = 0; j < 4; ++j) {
                const int rg = r0 + wr * 64 + mi * 16 + (lane >> 4) * 4 + j;
                Call[(size_t)rg * NO_ + o] = f2bf(acc[mi][ni][j] + bz);
            }
    }
}

// ------------------------------------------------- K3: V cols of Call -> vt[b][w][c][h]
__global__ __launch_bounds__(256) void k_transpose_v(const u16* __restrict__ Call, u16* __restrict__ vt) {
    __shared__ u16 tile[64][65];
    const int bw = blockIdx.x;
    const int h0 = (blockIdx.y & 1) * 64;
    const int c0 = (blockIdx.y >> 1) * 64;
    const int t = threadIdx.x, r = t >> 4, seg = t & 15;
#pragma unroll
    for (int rr = 0; rr < 4; ++rr) {
        const int hl = rr * 16 + r;
        ushort4 v = *(const ushort4*)&Call[(size_t)(bw * 128 + h0 + hl) * NO_ + 128 + c0 + seg * 4];
        tile[hl][seg * 4 + 0] = v.x; tile[hl][seg * 4 + 1] = v.y;
        tile[hl][seg * 4 + 2] = v.z; tile[hl][seg * 4 + 3] = v.w;
    }
    __syncthreads();
#pragma unroll
    for (int rr = 0; rr < 4; ++rr) {
        const int cl = rr * 16 + r;
        ushort4 u;
        u.x = tile[seg * 4 + 0][cl]; u.y = tile[seg * 4 + 1][cl];
        u.z = tile[seg * 4 + 2][cl]; u.w = tile[seg * 4 + 3][cl];
        *(ushort4*)&vt[((size_t)bw * 512 + c0 + cl) * 128 + h0 + seg * 4] = u;
    }
}

// ------------------------------------------------- K4: per-(b,w) axial attention
__global__ __launch_bounds__(256) void k_attn(const u16* __restrict__ Call, const u16* __restrict__ vt,
                                              u16* __restrict__ outws) {
    __shared__ __align__(16) float E[128][132];
    __shared__ float Rinv[128];
    const int bw = blockIdx.x;
    const int t = threadIdx.x;
    const int lane = t & 63;
    const int wr = t >> 7;
    const int wc = (t >> 6) & 1;
    const int lr = lane & 15, lk = (lane >> 4) * 8;
    const size_t rowbase = (size_t)bw * 128;

    // ---- energy = Q K^T  (K-dim = 64 channels)
    f32x4 e[4][4] = {};
#pragma unroll
    for (int kk = 0; kk < 2; ++kk) {
        s16x8 fq[4], fk[4];
#pragma unroll
        for (int mi = 0; mi < 4; ++mi)
            fq[mi] = *(const s16x8*)&Call[(rowbase + wr * 64 + mi * 16 + lr) * NO_ + kk * 32 + lk];
#pragma unroll
        for (int ni = 0; ni < 4; ++ni)
            fk[ni] = *(const s16x8*)&Call[(rowbase + wc * 64 + ni * 16 + lr) * NO_ + 64 + kk * 32 + lk];
#pragma unroll
        for (int mi = 0; mi < 4; ++mi)
#pragma unroll
            for (int ni = 0; ni < 4; ++ni)
                e[mi][ni] = __builtin_amdgcn_mfma_f32_16x16x32_bf16(fq[mi], fk[ni], e[mi][ni], 0, 0, 0);
    }
#pragma unroll
    for (int mi = 0; mi < 4; ++mi)
#pragma unroll
        for (int ni = 0; ni < 4; ++ni)
#pragma unroll
            for (int j = 0; j < 4; ++j)
                E[wr * 64 + mi * 16 + (lane >> 4) * 4 + j][wc * 64 + ni * 16 + lr] = e[mi][ni][j];
    __syncthreads();

    // ---- softmax over g (rows h), exp in place, 2 threads per row
    {
        const int h = t >> 1, hf = (t & 1) * 64;
        float m = -1e30f;
        for (int i = 0; i < 64; ++i) m = fmaxf(m, E[h][hf + i]);
        m = fmaxf(m, __shfl_xor(m, 1));
        float s = 0.f;
        for (int i = 0; i < 64; ++i) {
            float p = __expf(E[h][hf + i] - m);
            E[h][hf + i] = p;
            s += p;
        }
        s += __shfl_xor(s, 1);
        if ((t & 1) == 0) Rinv[h] = 1.0f / s;
    }
    __syncthreads();

    float rv[4][4];
#pragma unroll
    for (int mi = 0; mi < 4; ++mi)
#pragma unroll
        for (int j = 0; j < 4; ++j)
            rv[mi][j] = Rinv[wr * 64 + mi * 16 + (lane >> 4) * 4 + j];

    // ---- P rows -> bf16 fragments ONCE (reused across the 4 c-chunks)
    s16x8 pa[4][4];   // [kk][mi], all indices compile-time after unroll
#pragma unroll
    for (int kk = 0; kk < 4; ++kk)
#pragma unroll
        for (int mi = 0; mi < 4; ++mi) {
            const float* ep = &E[wr * 64 + mi * 16 + lr][kk * 32 + lk];
            float4 v0 = *(const float4*)ep;
            float4 v1 = *(const float4*)(ep + 4);
            s16x8 a;
            a[0] = (short)f2bf(v0.x); a[1] = (short)f2bf(v0.y);
            a[2] = (short)f2bf(v0.z); a[3] = (short)f2bf(v0.w);
            a[4] = (short)f2bf(v1.x); a[5] = (short)f2bf(v1.y);
            a[6] = (short)f2bf(v1.z); a[7] = (short)f2bf(v1.w);
            pa[kk][mi] = a;
        }

    // ---- out = P V  (K-dim = 128 g, N = 512 c in 4 chunks)
    for (int cc = 0; cc < 4; ++cc) {
        f32x4 acc[4][4] = {};
#pragma unroll
        for (int kk = 0; kk < 4; ++kk) {
            s16x8 fb[4];
#pragma unroll
            for (int ni = 0; ni < 4; ++ni)
                fb[ni] = *(const s16x8*)&vt[((size_t)bw * 512 + cc * 128 + wc * 64 + ni * 16 + lr) * 128 + kk * 32 + lk];
#pragma unroll
            for (int mi = 0; mi < 4; ++mi)
#pragma unroll
                for (int ni = 0; ni < 4; ++ni)
                    acc[mi][ni] = __builtin_amdgcn_mfma_f32_16x16x32_bf16(pa[kk][mi], fb[ni], acc[mi][ni], 0, 0, 0);
        }
#pragma unroll
        for (int ni = 0; ni < 4; ++ni) {
            const int c = cc * 128 + wc * 64 + ni * 16 + lr;
#pragma unroll
            for (int mi = 0; mi < 4; ++mi)
#pragma unroll
                for (int j = 0; j < 4; ++j) {
                    const int hh = wr * 64 + mi * 16 + (lane >> 4) * 4 + j;
                    outws[(rowbase + hh) * 512 + c] = f2bf(acc[mi][ni][j] * rv[mi][j]);
                }
        }
    }
}

// ------------------------------------------------- K5: out = gamma*out_ws^T + x
__global__ __launch_bounds__(256) void k_merge(const u16* __restrict__ outws, const float* __restrict__ x,
                                               const float* __restrict__ gamma, float* __restrict__ out) {
    __shared__ float tile[64][65];
    const int b  = blockIdx.x >> 7;
    const int h  = blockIdx.x & 127;
    const int c0 = (blockIdx.y >> 1) * 64;
    const int w0 = (blockIdx.y & 1) * 64;
    const float g = gamma[0];
    const int t = threadIdx.x, r = t >> 4, seg = t & 15;
#pragma unroll
    for (int rr = 0; rr < 4; ++rr) {
        const int w = rr * 16 + r;
        ushort4 v = *(const ushort4*)(outws + ((size_t)((b * W_ + w0 + w) * H_) + h) * C_ + c0 + seg * 4);
        tile[w][seg * 4 + 0] = bf2f(v.x); tile[w][seg * 4 + 1] = bf2f(v.y);
        tile[w][seg * 4 + 2] = bf2f(v.z); tile[w][seg * 4 + 3] = bf2f(v.w);
    }
    __syncthreads();
#pragma unroll
    for (int rr = 0; rr < 4; ++rr) {
        const int c = rr * 16 + r;
        const size_t base = ((size_t)(b * C_ + c0 + c) * H_ + h) * W_ + w0 + seg * 4;
        float4 xv = *(const float4*)(x + base);
        float4 o;
        o.x = g * tile[seg * 4 + 0][c] + xv.x;
        o.y = g * tile[seg * 4 + 1][c] + xv.y;
        o.z = g * tile[seg * 4 + 2][c] + xv.z;
        o.w = g * tile[seg * 4 + 3][c] + xv.w;
        *(float4*)(out + base) = o;
    }
}

extern "C" void kernel_launch(void* const* d_in, const int* in_sizes, int n_in,
                              void* d_out, int out_size, void* d_ws, size_t ws_size,
                              hipStream_t stream) {
    const float* x     = (const float*)d_in[0];
    const float* Wq    = (const float*)d_in[1];
    const float* bq    = (const float*)d_in[2];
    const float* Wk    = (const float*)d_in[3];
    const float* bk    = (const float*)d_in[4];
    const float* Wv    = (const float*)d_in[5];
    const float* bv    = (const float*)d_in[6];
    const float* gamma = (const float*)d_in[7];

    char* ws = (char*)d_ws;
    u16*   Wcat  = (u16*)ws;                                   //   0.66 MB
    float* bcat  = (float*)(ws + 655360);                      //   2.5 KB
    u16*   xT    = (u16*)(ws + (1u << 20));                    //  67.1 MB  (reused as out_ws)
    u16*   Call  = (u16*)(ws + (1u << 20) + 67108864);         //  83.9 MB
    u16*   outws = xT;                                         //  xT dead after k_gemm
    u16*   vt    = (u16*)d_out;                                //  first 67 MB of d_out (134 MB); dead before k_merge writes

    k_convw<<<dim3((NO_ * C_ + 255) / 256), 256, 0, stream>>>(Wq, bq, Wk, bk, Wv, bv, Wcat, bcat);
    k_transpose_x<<<dim3(B_ * H_, 16), 256, 0, stream>>>(x, xT);
    k_gemm<<<dim3(512, 5), 256, 0, stream>>>(xT, Wcat, bcat, Call);
    k_transpose_v<<<dim3(B_ * W_, 16), 256, 0, stream>>>(Call, vt);
    k_attn<<<dim3(B_ * W_), 256, 0, stream>>>(Call, vt, outws);
    k_merge<<<dim3(B_ * H_, 16), 256, 0, stream>>>(outws, x, gamma, (float*)d_out);
}

// Round 3
// 208.214 us; speedup vs baseline: 1.1270x; 1.1270x over previous
//
#include <hip/hip_runtime.h>
#include <hip/hip_bf16.h>

typedef float f32x4 __attribute__((ext_vector_type(4)));
typedef short s16x8 __attribute__((ext_vector_type(8)));
typedef unsigned short u16;

#define B_ 4
#define C_ 512
#define H_ 128
#define W_ 128
#define NO_ 640   // 64 q + 64 k + 512 v output channels

__device__ __forceinline__ u16 f2bf(float f) {
    __hip_bfloat16 h = __float2bfloat16(f);
    union { __hip_bfloat16 h; u16 u; } cv; cv.h = h; return cv.u;
}
__device__ __forceinline__ float bf2f(u16 u) {
    union { unsigned u; float f; } cv; cv.u = ((unsigned)u) << 16; return cv.f;
}

// async global->LDS, 16B per lane; LDS dest must be wave_base + lane*16
__device__ __forceinline__ void gld16(const u16* g, u16* l) {
    __builtin_amdgcn_global_load_lds(
        (const __attribute__((address_space(1))) void*)g,
        (__attribute__((address_space(3))) void*)l, 16, 0, 0);
}

// ---------------------------------------------------------------- K0: weights
__global__ __launch_bounds__(256) void k_convw(const float* __restrict__ Wq, const float* __restrict__ bq,
                                               const float* __restrict__ Wk, const float* __restrict__ bk,
                                               const float* __restrict__ Wv, const float* __restrict__ bv,
                                               u16* __restrict__ Wcat, float* __restrict__ bcat) {
    const int idx = blockIdx.x * 256 + threadIdx.x;
    if (idx < NO_ * C_) {
        const int o = idx >> 9, c = idx & 511;
        float v;
        if (o < 64)       v = Wq[o * C_ + c];
        else if (o < 128) v = Wk[(o - 64) * C_ + c];
        else              v = Wv[(o - 128) * C_ + c];
        Wcat[idx] = f2bf(v);
    }
    if (idx < NO_) {
        float v = (idx < 64) ? bq[idx] : ((idx < 128) ? bk[idx - 64] : bv[idx - 128]);
        bcat[idx] = v;
    }
}

// ------------------------------------------------- K1: x[B,C,H,W] -> xT[b][w][h][c] bf16
__global__ __launch_bounds__(256) void k_transpose_x(const float* __restrict__ x, u16* __restrict__ xT) {
    __shared__ float tile[64][65];
    const int b  = blockIdx.x >> 7;
    const int h  = blockIdx.x & 127;
    const int c0 = (blockIdx.y >> 1) * 64;
    const int w0 = (blockIdx.y & 1) * 64;
    const int t = threadIdx.x, r = t >> 4, seg = t & 15;
    const float* xp = x + (size_t)b * C_ * H_ * W_ + (size_t)h * W_;
#pragma unroll
    for (int rr = 0; rr < 4; ++rr) {
        const int c = rr * 16 + r;
        float4 v = *(const float4*)(xp + (size_t)(c0 + c) * (H_ * W_) + w0 + seg * 4);
        tile[c][seg * 4 + 0] = v.x; tile[c][seg * 4 + 1] = v.y;
        tile[c][seg * 4 + 2] = v.z; tile[c][seg * 4 + 3] = v.w;
    }
    __syncthreads();
#pragma unroll
    for (int rr = 0; rr < 4; ++rr) {
        const int w = rr * 16 + r;
        ushort4 u;
        u.x = f2bf(tile[seg * 4 + 0][w]); u.y = f2bf(tile[seg * 4 + 1][w]);
        u.z = f2bf(tile[seg * 4 + 2][w]); u.w = f2bf(tile[seg * 4 + 3][w]);
        *(ushort4*)(xT + ((size_t)((b * W_ + w0 + w) * H_ + h)) * C_ + c0 + seg * 4) = u;
    }
}

// ------------------------------------------------- K2: GEMM + fused V-transpose epilogue
// 128x128 tile, BK=32, 4 waves, 2-phase dbuf global_load_lds staging.
// blockIdx.x = n-tile (0..4), blockIdx.y = row-panel (= bw).
// n==0 -> Q/K channels written to Call[row][128]; n>=1 -> V channels transposed
// through LDS and written as vt[(bw*512 + c)*128 + h].
__global__ __launch_bounds__(256) void k_gemm(const u16* __restrict__ A, const u16* __restrict__ Wc,
                                              const float* __restrict__ bias, u16* __restrict__ Call,
                                              u16* __restrict__ vt) {
    __shared__ __align__(16) u16 smem[17408];   // 34.8 KB: staging dbuf (32KB) / transpose tile (34.8KB)
    u16* SA0 = smem;               // [128][32]
    u16* SA1 = smem + 4096;
    u16* SB0 = smem + 8192;
    u16* SB1 = smem + 12288;
    const int t = threadIdx.x;
    const int lane = t & 63;
    const int wr = t >> 7;
    const int wc = (t >> 6) & 1;
    const int q4 = lane >> 4;
    const int n  = blockIdx.x;
    const int n0 = n * 128;
    const int r0 = blockIdx.y * 128;
    const int srow = t >> 2, sseg = (t & 3) * 8;
    const int lr = lane & 15, lk = q4 * 8;
    const u16* pa0 = A  + (size_t)(r0 + srow) * C_ + sseg;
    const u16* pa1 = pa0 + (size_t)64 * C_;
    const u16* pb0 = Wc + (size_t)(n0 + srow) * C_ + sseg;
    const u16* pb1 = pb0 + (size_t)64 * C_;

#define STAGE(SA, SB, kk)                          \
    do {                                           \
        gld16(pa0 + (kk), &(SA)[t * 8]);           \
        gld16(pa1 + (kk), &(SA)[2048 + t * 8]);    \
        gld16(pb0 + (kk), &(SB)[t * 8]);           \
        gld16(pb1 + (kk), &(SB)[2048 + t * 8]);    \
    } while (0)

    f32x4 acc[4][4] = {};
    STAGE(SA0, SB0, 0);
    __syncthreads();
    int cur = 0;
#pragma unroll 2
    for (int it = 0; it < 16; ++it) {
        u16* sa = cur ? SA1 : SA0;
        u16* sb = cur ? SB1 : SB0;
        if (it < 15) {
            if (cur) STAGE(SA0, SB0, (it + 1) * 32);
            else     STAGE(SA1, SB1, (it + 1) * 32);
        }
        s16x8 fa[4], fb[4];
#pragma unroll
        for (int mi = 0; mi < 4; ++mi)
            fa[mi] = *(const s16x8*)&sa[(wr * 64 + mi * 16 + lr) * 32 + lk];
#pragma unroll
        for (int ni = 0; ni < 4; ++ni)
            fb[ni] = *(const s16x8*)&sb[(wc * 64 + ni * 16 + lr) * 32 + lk];
#pragma unroll
        for (int mi = 0; mi < 4; ++mi)
#pragma unroll
            for (int ni = 0; ni < 4; ++ni)
                acc[mi][ni] = __builtin_amdgcn_mfma_f32_16x16x32_bf16(fa[mi], fb[ni], acc[mi][ni], 0, 0, 0);
        __syncthreads();   // drains vmcnt(0): next-tile stage landed; cur-tile reads done
        cur ^= 1;
    }
#undef STAGE

    if (n == 0) {
        // Q/K: direct row-major store Call[row][o], o = 0..127
#pragma unroll
        for (int ni = 0; ni < 4; ++ni) {
            const int o = wc * 64 + ni * 16 + lr;
            const float bz = bias[o];
#pragma unroll
            for (int mi = 0; mi < 4; ++mi)
#pragma unroll
                for (int j = 0; j < 4; ++j) {
                    const int rg = r0 + wr * 64 + mi * 16 + q4 * 4 + j;
                    Call[(size_t)rg * 128 + o] = f2bf(acc[mi][ni][j] + bz);
                }
        }
    } else {
        // V: transpose via LDS -> vt[(bw*512 + c)*128 + h]
        u16* T = smem;   // [128][136] u16, padded stride (272B = 17*16 -> b128-aligned rows)
        const int bw = blockIdx.y;
#pragma unroll
        for (int ni = 0; ni < 4; ++ni) {
            const int c_l = wc * 64 + ni * 16 + lr;
            const float bz = bias[n0 + c_l];
#pragma unroll
            for (int mi = 0; mi < 4; ++mi) {
                ushort4 u4;
                u4.x = f2bf(acc[mi][ni][0] + bz);
                u4.y = f2bf(acc[mi][ni][1] + bz);
                u4.z = f2bf(acc[mi][ni][2] + bz);
                u4.w = f2bf(acc[mi][ni][3] + bz);
                *(ushort4*)&T[c_l * 136 + wr * 64 + mi * 16 + q4 * 4] = u4;
            }
        }
        __syncthreads();
        const int seg = t & 15;           // 16-byte segment within a 128-u16 row
        const int crb = t >> 4;           // 16 rows per round
#pragma unroll
        for (int rr = 0; rr < 8; ++rr) {
            const int c_l = rr * 16 + crb;
            s16x8 v = *(const s16x8*)&T[c_l * 136 + seg * 8];
            *(s16x8*)&vt[((size_t)bw * 512 + (n - 1) * 128 + c_l) * 128 + seg * 8] = v;
        }
    }
}

// ------------------------------------------------- K4: per-(b,w) axial attention
__global__ __launch_bounds__(256) void k_attn(const u16* __restrict__ Call, const u16* __restrict__ vt,
                                              u16* __restrict__ outws) {
    __shared__ __align__(16) float E[128][132];
    __shared__ float Rinv[128];
    const int bw = blockIdx.x;
    const int t = threadIdx.x;
    const int lane = t & 63;
    const int wr = t >> 7;
    const int wc = (t >> 6) & 1;
    const int lr = lane & 15, lk = (lane >> 4) * 8;
    const size_t rowbase = (size_t)bw * 128;

    // ---- energy = Q K^T  (K-dim = 64 channels); Call stride is 128 now
    f32x4 e[4][4] = {};
#pragma unroll
    for (int kk = 0; kk < 2; ++kk) {
        s16x8 fq[4], fk[4];
#pragma unroll
        for (int mi = 0; mi < 4; ++mi)
            fq[mi] = *(const s16x8*)&Call[(rowbase + wr * 64 + mi * 16 + lr) * 128 + kk * 32 + lk];
#pragma unroll
        for (int ni = 0; ni < 4; ++ni)
            fk[ni] = *(const s16x8*)&Call[(rowbase + wc * 64 + ni * 16 + lr) * 128 + 64 + kk * 32 + lk];
#pragma unroll
        for (int mi = 0; mi < 4; ++mi)
#pragma unroll
            for (int ni = 0; ni < 4; ++ni)
                e[mi][ni] = __builtin_amdgcn_mfma_f32_16x16x32_bf16(fq[mi], fk[ni], e[mi][ni], 0, 0, 0);
    }
#pragma unroll
    for (int mi = 0; mi < 4; ++mi)
#pragma unroll
        for (int ni = 0; ni < 4; ++ni)
#pragma unroll
            for (int j = 0; j < 4; ++j)
                E[wr * 64 + mi * 16 + (lane >> 4) * 4 + j][wc * 64 + ni * 16 + lr] = e[mi][ni][j];
    __syncthreads();

    // ---- softmax over g (rows h), exp in place, 2 threads per row
    {
        const int h = t >> 1, hf = (t & 1) * 64;
        float m = -1e30f;
        for (int i = 0; i < 64; ++i) m = fmaxf(m, E[h][hf + i]);
        m = fmaxf(m, __shfl_xor(m, 1));
        float s = 0.f;
        for (int i = 0; i < 64; ++i) {
            float p = __expf(E[h][hf + i] - m);
            E[h][hf + i] = p;
            s += p;
        }
        s += __shfl_xor(s, 1);
        if ((t & 1) == 0) Rinv[h] = 1.0f / s;
    }
    __syncthreads();

    float rv[4][4];
#pragma unroll
    for (int mi = 0; mi < 4; ++mi)
#pragma unroll
        for (int j = 0; j < 4; ++j)
            rv[mi][j] = Rinv[wr * 64 + mi * 16 + (lane >> 4) * 4 + j];

    // ---- P rows -> bf16 fragments ONCE (reused across the 4 c-chunks)
    s16x8 pa[4][4];
#pragma unroll
    for (int kk = 0; kk < 4; ++kk)
#pragma unroll
        for (int mi = 0; mi < 4; ++mi) {
            const float* ep = &E[wr * 64 + mi * 16 + lr][kk * 32 + lk];
            float4 v0 = *(const float4*)ep;
            float4 v1 = *(const float4*)(ep + 4);
            s16x8 a;
            a[0] = (short)f2bf(v0.x); a[1] = (short)f2bf(v0.y);
            a[2] = (short)f2bf(v0.z); a[3] = (short)f2bf(v0.w);
            a[4] = (short)f2bf(v1.x); a[5] = (short)f2bf(v1.y);
            a[6] = (short)f2bf(v1.z); a[7] = (short)f2bf(v1.w);
            pa[kk][mi] = a;
        }

    // ---- out = P V  (K-dim = 128 g, N = 512 c in 4 chunks)
    for (int cc = 0; cc < 4; ++cc) {
        f32x4 acc[4][4] = {};
#pragma unroll
        for (int kk = 0; kk < 4; ++kk) {
            s16x8 fb[4];
#pragma unroll
            for (int ni = 0; ni < 4; ++ni)
                fb[ni] = *(const s16x8*)&vt[((size_t)bw * 512 + cc * 128 + wc * 64 + ni * 16 + lr) * 128 + kk * 32 + lk];
#pragma unroll
            for (int mi = 0; mi < 4; ++mi)
#pragma unroll
                for (int ni = 0; ni < 4; ++ni)
                    acc[mi][ni] = __builtin_amdgcn_mfma_f32_16x16x32_bf16(pa[kk][mi], fb[ni], acc[mi][ni], 0, 0, 0);
        }
#pragma unroll
        for (int ni = 0; ni < 4; ++ni) {
            const int c = cc * 128 + wc * 64 + ni * 16 + lr;
#pragma unroll
            for (int mi = 0; mi < 4; ++mi)
#pragma unroll
                for (int j = 0; j < 4; ++j) {
                    const int hh = wr * 64 + mi * 16 + (lane >> 4) * 4 + j;
                    outws[(rowbase + hh) * 512 + c] = f2bf(acc[mi][ni][j] * rv[mi][j]);
                }
        }
    }
}

// ------------------------------------------------- K5: out = gamma*out_ws^T + x
__global__ __launch_bounds__(256) void k_merge(const u16* __restrict__ outws, const float* __restrict__ x,
                                               const float* __restrict__ gamma, float* __restrict__ out) {
    __shared__ float tile[64][65];
    const int b  = blockIdx.x >> 7;
    const int h  = blockIdx.x & 127;
    const int c0 = (blockIdx.y >> 1) * 64;
    const int w0 = (blockIdx.y & 1) * 64;
    const float g = gamma[0];
    const int t = threadIdx.x, r = t >> 4, seg = t & 15;
#pragma unroll
    for (int rr = 0; rr < 4; ++rr) {
        const int w = rr * 16 + r;
        ushort4 v = *(const ushort4*)(outws + ((size_t)((b * W_ + w0 + w) * H_) + h) * C_ + c0 + seg * 4);
        tile[w][seg * 4 + 0] = bf2f(v.x); tile[w][seg * 4 + 1] = bf2f(v.y);
        tile[w][seg * 4 + 2] = bf2f(v.z); tile[w][seg * 4 + 3] = bf2f(v.w);
    }
    __syncthreads();
#pragma unroll
    for (int rr = 0; rr < 4; ++rr) {
        const int c = rr * 16 + r;
        const size_t base = ((size_t)(b * C_ + c0 + c) * H_ + h) * W_ + w0 + seg * 4;
        float4 xv = *(const float4*)(x + base);
        float4 o;
        o.x = g * tile[seg * 4 + 0][c] + xv.x;
        o.y = g * tile[seg * 4 + 1][c] + xv.y;
        o.z = g * tile[seg * 4 + 2][c] + xv.z;
        o.w = g * tile[seg * 4 + 3][c] + xv.w;
        *(float4*)(out + base) = o;
    }
}

extern "C" void kernel_launch(void* const* d_in, const int* in_sizes, int n_in,
                              void* d_out, int out_size, void* d_ws, size_t ws_size,
                              hipStream_t stream) {
    const float* x     = (const float*)d_in[0];
    const float* Wq    = (const float*)d_in[1];
    const float* bq    = (const float*)d_in[2];
    const float* Wk    = (const float*)d_in[3];
    const float* bk    = (const float*)d_in[4];
    const float* Wv    = (const float*)d_in[5];
    const float* bv    = (const float*)d_in[6];
    const float* gamma = (const float*)d_in[7];

    char* ws = (char*)d_ws;
    u16*   Wcat  = (u16*)ws;                                   //   0.66 MB
    float* bcat  = (float*)(ws + 655360);                      //   2.5 KB
    u16*   xT    = (u16*)(ws + (1u << 20));                    //  67.1 MB  (reused as out_ws)
    u16*   Call  = (u16*)(ws + (1u << 20) + 67108864);         //  16.8 MB  (Q/K only, stride 128)
    u16*   outws = xT;                                         //  xT dead after k_gemm
    u16*   vt    = (u16*)d_out;                                //  first 67 MB of d_out; dead before k_merge writes

    k_convw<<<dim3((NO_ * C_ + 255) / 256), 256, 0, stream>>>(Wq, bq, Wk, bk, Wv, bv, Wcat, bcat);
    k_transpose_x<<<dim3(B_ * H_, 16), 256, 0, stream>>>(x, xT);
    k_gemm<<<dim3(5, 512), 256, 0, stream>>>(xT, Wcat, bcat, Call, vt);
    k_attn<<<dim3(B_ * W_), 256, 0, stream>>>(Call, vt, outws);
    k_merge<<<dim3(B_ * H_, 16), 256, 0, stream>>>(outws, x, gamma, (float*)d_out);
}

// Round 4
// 203.640 us; speedup vs baseline: 1.1523x; 1.0225x over previous
//
#include <hip/hip_runtime.h>
#include <hip/hip_bf16.h>

typedef float f32x4 __attribute__((ext_vector_type(4)));
typedef short s16x8 __attribute__((ext_vector_type(8)));
typedef unsigned short u16;

#define B_ 4
#define C_ 512
#define H_ 128
#define W_ 128
#define NO_ 640   // 64 q + 64 k + 512 v output channels

__device__ __forceinline__ u16 f2bf(float f) {
    __hip_bfloat16 h = __float2bfloat16(f);
    union { __hip_bfloat16 h; u16 u; } cv; cv.h = h; return cv.u;
}
__device__ __forceinline__ float bf2f(u16 u) {
    union { unsigned u; float f; } cv; cv.u = ((unsigned)u) << 16; return cv.f;
}

// async global->LDS, 16B per lane; LDS dest must be wave_base + lane*16
__device__ __forceinline__ void gld16(const u16* g, u16* l) {
    __builtin_amdgcn_global_load_lds(
        (const __attribute__((address_space(1))) void*)g,
        (__attribute__((address_space(3))) void*)l, 16, 0, 0);
}

// ---------------------------------------------------------------- K0: weights
__global__ __launch_bounds__(256) void k_convw(const float* __restrict__ Wq, const float* __restrict__ bq,
                                               const float* __restrict__ Wk, const float* __restrict__ bk,
                                               const float* __restrict__ Wv, const float* __restrict__ bv,
                                               u16* __restrict__ Wcat, float* __restrict__ bcat) {
    const int idx = blockIdx.x * 256 + threadIdx.x;
    if (idx < NO_ * C_) {
        const int o = idx >> 9, c = idx & 511;
        float v;
        if (o < 64)       v = Wq[o * C_ + c];
        else if (o < 128) v = Wk[(o - 64) * C_ + c];
        else              v = Wv[(o - 128) * C_ + c];
        Wcat[idx] = f2bf(v);
    }
    if (idx < NO_) {
        float v = (idx < 64) ? bq[idx] : ((idx < 128) ? bk[idx - 64] : bv[idx - 128]);
        bcat[idx] = v;
    }
}

// ------------------------------------------------- K1: x[B,C,H,W] -> xT[b][w][h][c] bf16
__global__ __launch_bounds__(256) void k_transpose_x(const float* __restrict__ x, u16* __restrict__ xT) {
    __shared__ float tile[64][65];
    const int b  = blockIdx.x >> 7;
    const int h  = blockIdx.x & 127;
    const int c0 = (blockIdx.y >> 1) * 64;
    const int w0 = (blockIdx.y & 1) * 64;
    const int t = threadIdx.x, r = t >> 4, seg = t & 15;
    const float* xp = x + (size_t)b * C_ * H_ * W_ + (size_t)h * W_;
#pragma unroll
    for (int rr = 0; rr < 4; ++rr) {
        const int c = rr * 16 + r;
        float4 v = *(const float4*)(xp + (size_t)(c0 + c) * (H_ * W_) + w0 + seg * 4);
        tile[c][seg * 4 + 0] = v.x; tile[c][seg * 4 + 1] = v.y;
        tile[c][seg * 4 + 2] = v.z; tile[c][seg * 4 + 3] = v.w;
    }
    __syncthreads();
#pragma unroll
    for (int rr = 0; rr < 4; ++rr) {
        const int w = rr * 16 + r;
        ushort4 u;
        u.x = f2bf(tile[seg * 4 + 0][w]); u.y = f2bf(tile[seg * 4 + 1][w]);
        u.z = f2bf(tile[seg * 4 + 2][w]); u.w = f2bf(tile[seg * 4 + 3][w]);
        *(ushort4*)(xT + ((size_t)((b * W_ + w0 + w) * H_ + h)) * C_ + c0 + seg * 4) = u;
    }
}

// ------------------------------------------------- K2: GEMM (BM=256,BN=128,BK=32, 8 waves)
// single-buffered gld16 staging, XCD-chunked swizzle, fused V-transpose epilogue.
// panel = 256 rows = (bw0, bw0+1); n==0 -> Q/K to Call[row][128]; n>=1 -> vt[(bw*512+c)*128+h]
__global__ __launch_bounds__(512) void k_gemm(const u16* __restrict__ A, const u16* __restrict__ Wc,
                                              const float* __restrict__ bias, u16* __restrict__ Call,
                                              u16* __restrict__ vt) {
    __shared__ __align__(16) u16 smem[16896];   // 33 KB: staging (24 KB) / T[64][264] (33 KB)
    u16* Al = smem;            // [256][32]
    u16* Bl = smem + 8192;     // [128][32]
    const int t = threadIdx.x;
    const int lane = t & 63;
    const int wave = t >> 6;
    const int wr = wave & 3;          // M quadrant (64 rows each)
    const int wc = wave >> 2;         // N half (64 cols each)
    const int q4 = lane >> 4;
    const int lr = lane & 15, lk = q4 * 8;

    // bijective XCD-chunk swizzle: 1280 blocks = 8 XCDs x 160; n fastest within a panel
    const int bid = blockIdx.x;
    const int wg = (bid & 7) * 160 + (bid >> 3);
    const int panel = wg / 5;
    const int n = wg - panel * 5;
    const int r0 = panel * 256;
    const int n0 = n * 128;

    const u16* pa0 = A  + (size_t)(r0 + (t >> 2)) * C_ + (t & 3) * 8;
    const u16* pa1 = pa0 + (size_t)128 * C_;
    const u16* pb  = Wc + (size_t)(n0 + (t >> 2)) * C_ + (t & 3) * 8;

    f32x4 acc[4][4] = {};
    for (int it = 0; it < 16; ++it) {
        const int kk = it * 32;
        gld16(pa0 + kk, &Al[t * 8]);
        gld16(pa1 + kk, &Al[4096 + t * 8]);
        gld16(pb  + kk, &Bl[t * 8]);
        __syncthreads();                       // staging visible
        s16x8 fa[4], fb[4];
#pragma unroll
        for (int mi = 0; mi < 4; ++mi)
            fa[mi] = *(const s16x8*)&Al[(wr * 64 + mi * 16 + lr) * 32 + lk];
#pragma unroll
        for (int ni = 0; ni < 4; ++ni)
            fb[ni] = *(const s16x8*)&Bl[(wc * 64 + ni * 16 + lr) * 32 + lk];
#pragma unroll
        for (int mi = 0; mi < 4; ++mi)
#pragma unroll
            for (int ni = 0; ni < 4; ++ni)
                acc[mi][ni] = __builtin_amdgcn_mfma_f32_16x16x32_bf16(fa[mi], fb[ni], acc[mi][ni], 0, 0, 0);
        __syncthreads();                       // reads done before next stage
    }

    if (n == 0) {
        // Q/K: Call[row][o], rows r0..r0+255, o = 0..127
#pragma unroll
        for (int ni = 0; ni < 4; ++ni) {
            const int o = wc * 64 + ni * 16 + lr;
            const float bz = bias[o];
#pragma unroll
            for (int mi = 0; mi < 4; ++mi)
#pragma unroll
                for (int j = 0; j < 4; ++j) {
                    const int rg = r0 + wr * 64 + mi * 16 + q4 * 4 + j;
                    Call[(size_t)rg * 128 + o] = f2bf(acc[mi][ni][j] + bz);
                }
        }
    } else {
        // V: two-pass transpose through T[64][264]; vt[(bw*512 + cg)*128 + h]
        u16* T = smem;
        const int bw0 = panel * 2;
#pragma unroll
        for (int P = 0; P < 2; ++P) {
            if (wc == P) {
#pragma unroll
                for (int ni = 0; ni < 4; ++ni) {
                    const int c_loc = ni * 16 + lr;                 // 0..63
                    const float bz = bias[n0 + P * 64 + c_loc];
#pragma unroll
                    for (int mi = 0; mi < 4; ++mi) {
                        ushort4 u4;
                        u4.x = f2bf(acc[mi][ni][0] + bz);
                        u4.y = f2bf(acc[mi][ni][1] + bz);
                        u4.z = f2bf(acc[mi][ni][2] + bz);
                        u4.w = f2bf(acc[mi][ni][3] + bz);
                        *(ushort4*)&T[c_loc * 264 + wr * 64 + mi * 16 + q4 * 4] = u4;
                    }
                }
            }
            __syncthreads();
            {
                const int c_loc = t >> 3, hseg = t & 7;
                const int cg = (n - 1) * 128 + P * 64 + c_loc;      // V channel 0..511
#pragma unroll
                for (int k = 0; k < 4; ++k) {
                    const int lh = hseg * 32 + k * 8;               // 0..255
                    const int bw = bw0 + (lh >> 7);
                    const int h  = lh & 127;
                    s16x8 v = *(const s16x8*)&T[c_loc * 264 + lh];
                    *(s16x8*)&vt[((size_t)bw * 512 + cg) * 128 + h] = v;
                }
            }
            __syncthreads();
        }
    }
}

// ------------------------------------------------- K4: per-(b,w) axial attention
__global__ __launch_bounds__(256) void k_attn(const u16* __restrict__ Call, const u16* __restrict__ vt,
                                              u16* __restrict__ outws) {
    __shared__ __align__(16) float E[128][132];
    __shared__ float Rinv[128];
    const int bw = blockIdx.x;
    const int t = threadIdx.x;
    const int lane = t & 63;
    const int wr = t >> 7;
    const int wc = (t >> 6) & 1;
    const int lr = lane & 15, lk = (lane >> 4) * 8;
    const size_t rowbase = (size_t)bw * 128;

    // ---- energy = Q K^T  (K-dim = 64 channels); Call stride 128
    f32x4 e[4][4] = {};
#pragma unroll
    for (int kk = 0; kk < 2; ++kk) {
        s16x8 fq[4], fk[4];
#pragma unroll
        for (int mi = 0; mi < 4; ++mi)
            fq[mi] = *(const s16x8*)&Call[(rowbase + wr * 64 + mi * 16 + lr) * 128 + kk * 32 + lk];
#pragma unroll
        for (int ni = 0; ni < 4; ++ni)
            fk[ni] = *(const s16x8*)&Call[(rowbase + wc * 64 + ni * 16 + lr) * 128 + 64 + kk * 32 + lk];
#pragma unroll
        for (int mi = 0; mi < 4; ++mi)
#pragma unroll
            for (int ni = 0; ni < 4; ++ni)
                e[mi][ni] = __builtin_amdgcn_mfma_f32_16x16x32_bf16(fq[mi], fk[ni], e[mi][ni], 0, 0, 0);
    }
#pragma unroll
    for (int mi = 0; mi < 4; ++mi)
#pragma unroll
        for (int ni = 0; ni < 4; ++ni)
#pragma unroll
            for (int j = 0; j < 4; ++j)
                E[wr * 64 + mi * 16 + (lane >> 4) * 4 + j][wc * 64 + ni * 16 + lr] = e[mi][ni][j];
    __syncthreads();

    // ---- softmax over g (rows h), exp in place, 2 threads per row
    {
        const int h = t >> 1, hf = (t & 1) * 64;
        float m = -1e30f;
        for (int i = 0; i < 64; ++i) m = fmaxf(m, E[h][hf + i]);
        m = fmaxf(m, __shfl_xor(m, 1));
        float s = 0.f;
        for (int i = 0; i < 64; ++i) {
            float p = __expf(E[h][hf + i] - m);
            E[h][hf + i] = p;
            s += p;
        }
        s += __shfl_xor(s, 1);
        if ((t & 1) == 0) Rinv[h] = 1.0f / s;
    }
    __syncthreads();

    float rv[4][4];
#pragma unroll
    for (int mi = 0; mi < 4; ++mi)
#pragma unroll
        for (int j = 0; j < 4; ++j)
            rv[mi][j] = Rinv[wr * 64 + mi * 16 + (lane >> 4) * 4 + j];

    // ---- P rows -> bf16 fragments ONCE
    s16x8 pa[4][4];
#pragma unroll
    for (int kk = 0; kk < 4; ++kk)
#pragma unroll
        for (int mi = 0; mi < 4; ++mi) {
            const float* ep = &E[wr * 64 + mi * 16 + lr][kk * 32 + lk];
            float4 v0 = *(const float4*)ep;
            float4 v1 = *(const float4*)(ep + 4);
            s16x8 a;
            a[0] = (short)f2bf(v0.x); a[1] = (short)f2bf(v0.y);
            a[2] = (short)f2bf(v0.z); a[3] = (short)f2bf(v0.w);
            a[4] = (short)f2bf(v1.x); a[5] = (short)f2bf(v1.y);
            a[6] = (short)f2bf(v1.z); a[7] = (short)f2bf(v1.w);
            pa[kk][mi] = a;
        }

    // ---- out = P V
    for (int cc = 0; cc < 4; ++cc) {
        f32x4 acc[4][4] = {};
#pragma unroll
        for (int kk = 0; kk < 4; ++kk) {
            s16x8 fb[4];
#pragma unroll
            for (int ni = 0; ni < 4; ++ni)
                fb[ni] = *(const s16x8*)&vt[((size_t)bw * 512 + cc * 128 + wc * 64 + ni * 16 + lr) * 128 + kk * 32 + lk];
#pragma unroll
            for (int mi = 0; mi < 4; ++mi)
#pragma unroll
                for (int ni = 0; ni < 4; ++ni)
                    acc[mi][ni] = __builtin_amdgcn_mfma_f32_16x16x32_bf16(pa[kk][mi], fb[ni], acc[mi][ni], 0, 0, 0);
        }
#pragma unroll
        for (int ni = 0; ni < 4; ++ni) {
            const int c = cc * 128 + wc * 64 + ni * 16 + lr;
#pragma unroll
            for (int mi = 0; mi < 4; ++mi)
#pragma unroll
                for (int j = 0; j < 4; ++j) {
                    const int hh = wr * 64 + mi * 16 + (lane >> 4) * 4 + j;
                    outws[(rowbase + hh) * 512 + c] = f2bf(acc[mi][ni][j] * rv[mi][j]);
                }
        }
    }
}

// ------------------------------------------------- K5: out = gamma*out_ws^T + x
__global__ __launch_bounds__(256) void k_merge(const u16* __restrict__ outws, const float* __restrict__ x,
                                               const float* __restrict__ gamma, float* __restrict__ out) {
    __shared__ float tile[64][65];
    const int b  = blockIdx.x >> 7;
    const int h  = blockIdx.x & 127;
    const int c0 = (blockIdx.y >> 1) * 64;
    const int w0 = (blockIdx.y & 1) * 64;
    const float g = gamma[0];
    const int t = threadIdx.x, r = t >> 4, seg = t & 15;
#pragma unroll
    for (int rr = 0; rr < 4; ++rr) {
        const int w = rr * 16 + r;
        ushort4 v = *(const ushort4*)(outws + ((size_t)((b * W_ + w0 + w) * H_) + h) * C_ + c0 + seg * 4);
        tile[w][seg * 4 + 0] = bf2f(v.x); tile[w][seg * 4 + 1] = bf2f(v.y);
        tile[w][seg * 4 + 2] = bf2f(v.z); tile[w][seg * 4 + 3] = bf2f(v.w);
    }
    __syncthreads();
#pragma unroll
    for (int rr = 0; rr < 4; ++rr) {
        const int c = rr * 16 + r;
        const size_t base = ((size_t)(b * C_ + c0 + c) * H_ + h) * W_ + w0 + seg * 4;
        float4 xv = *(const float4*)(x + base);
        float4 o;
        o.x = g * tile[seg * 4 + 0][c] + xv.x;
        o.y = g * tile[seg * 4 + 1][c] + xv.y;
        o.z = g * tile[seg * 4 + 2][c] + xv.z;
        o.w = g * tile[seg * 4 + 3][c] + xv.w;
        *(float4*)(out + base) = o;
    }
}

extern "C" void kernel_launch(void* const* d_in, const int* in_sizes, int n_in,
                              void* d_out, int out_size, void* d_ws, size_t ws_size,
                              hipStream_t stream) {
    const float* x     = (const float*)d_in[0];
    const float* Wq    = (const float*)d_in[1];
    const float* bq    = (const float*)d_in[2];
    const float* Wk    = (const float*)d_in[3];
    const float* bk    = (const float*)d_in[4];
    const float* Wv    = (const float*)d_in[5];
    const float* bv    = (const float*)d_in[6];
    const float* gamma = (const float*)d_in[7];

    char* ws = (char*)d_ws;
    u16*   Wcat  = (u16*)ws;                                   //   0.66 MB
    float* bcat  = (float*)(ws + 655360);                      //   2.5 KB
    u16*   xT    = (u16*)(ws + (1u << 20));                    //  67.1 MB  (reused as out_ws)
    u16*   Call  = (u16*)(ws + (1u << 20) + 67108864);         //  16.8 MB  (Q/K only, stride 128)
    u16*   outws = xT;                                         //  xT dead after k_gemm
    u16*   vt    = (u16*)d_out;                                //  first 67 MB of d_out; dead before k_merge writes

    k_convw<<<dim3((NO_ * C_ + 255) / 256), 256, 0, stream>>>(Wq, bq, Wk, bk, Wv, bv, Wcat, bcat);
    k_transpose_x<<<dim3(B_ * H_, 16), 256, 0, stream>>>(x, xT);
    k_gemm<<<dim3(1280), 512, 0, stream>>>(xT, Wcat, bcat, Call, vt);
    k_attn<<<dim3(B_ * W_), 256, 0, stream>>>(Call, vt, outws);
    k_merge<<<dim3(B_ * H_, 16), 256, 0, stream>>>(outws, x, gamma, (float*)d_out);
}

// Round 5
// 198.186 us; speedup vs baseline: 1.1840x; 1.0275x over previous
//
#include <hip/hip_runtime.h>
#include <hip/hip_bf16.h>

typedef float f32x4 __attribute__((ext_vector_type(4)));
typedef short s16x8 __attribute__((ext_vector_type(8)));
typedef unsigned short u16;

#define B_ 4
#define C_ 512
#define H_ 128
#define W_ 128
#define NO_ 640   // 64 q + 64 k + 512 v output channels

__device__ __forceinline__ u16 f2bf(float f) {
    __hip_bfloat16 h = __float2bfloat16(f);
    union { __hip_bfloat16 h; u16 u; } cv; cv.h = h; return cv.u;
}
__device__ __forceinline__ float bf2f(u16 u) {
    union { unsigned u; float f; } cv; cv.u = ((unsigned)u) << 16; return cv.f;
}

// async global->LDS, 16B per lane; LDS dest must be wave_base + lane*16
__device__ __forceinline__ void gld16(const u16* g, u16* l) {
    __builtin_amdgcn_global_load_lds(
        (const __attribute__((address_space(1))) void*)g,
        (__attribute__((address_space(3))) void*)l, 16, 0, 0);
}

// ---------------------------------------------------------------- K0: weights
__global__ __launch_bounds__(256) void k_convw(const float* __restrict__ Wq, const float* __restrict__ bq,
                                               const float* __restrict__ Wk, const float* __restrict__ bk,
                                               const float* __restrict__ Wv, const float* __restrict__ bv,
                                               u16* __restrict__ Wcat, float* __restrict__ bcat) {
    const int idx = blockIdx.x * 256 + threadIdx.x;
    if (idx < NO_ * C_) {
        const int o = idx >> 9, c = idx & 511;
        float v;
        if (o < 64)       v = Wq[o * C_ + c];
        else if (o < 128) v = Wk[(o - 64) * C_ + c];
        else              v = Wv[(o - 128) * C_ + c];
        Wcat[idx] = f2bf(v);
    }
    if (idx < NO_) {
        float v = (idx < 64) ? bq[idx] : ((idx < 128) ? bk[idx - 64] : bv[idx - 128]);
        bcat[idx] = v;
    }
}

// ------------------------------------------------- K1: x[B,C,H,W] -> xT[b][w][h][c] bf16
__global__ __launch_bounds__(256) void k_transpose_x(const float* __restrict__ x, u16* __restrict__ xT) {
    __shared__ float tile[64][65];
    const int b  = blockIdx.x >> 7;
    const int h  = blockIdx.x & 127;
    const int c0 = (blockIdx.y >> 1) * 64;
    const int w0 = (blockIdx.y & 1) * 64;
    const int t = threadIdx.x, r = t >> 4, seg = t & 15;
    const float* xp = x + (size_t)b * C_ * H_ * W_ + (size_t)h * W_;
#pragma unroll
    for (int rr = 0; rr < 4; ++rr) {
        const int c = rr * 16 + r;
        float4 v = *(const float4*)(xp + (size_t)(c0 + c) * (H_ * W_) + w0 + seg * 4);
        tile[c][seg * 4 + 0] = v.x; tile[c][seg * 4 + 1] = v.y;
        tile[c][seg * 4 + 2] = v.z; tile[c][seg * 4 + 3] = v.w;
    }
    __syncthreads();
#pragma unroll
    for (int rr = 0; rr < 4; ++rr) {
        const int w = rr * 16 + r;
        ushort4 u;
        u.x = f2bf(tile[seg * 4 + 0][w]); u.y = f2bf(tile[seg * 4 + 1][w]);
        u.z = f2bf(tile[seg * 4 + 2][w]); u.w = f2bf(tile[seg * 4 + 3][w]);
        *(ushort4*)(xT + ((size_t)((b * W_ + w0 + w) * H_ + h)) * C_ + c0 + seg * 4) = u;
    }
}

// ------------------------------------------------- K2: GEMM, counted-vmcnt ring-3 schedule
// BM=256, BN=128, BK=64, 8 waves (4M x 2N), LDS = 3 x (A 32KB + B 16KB) = 144 KB.
// T2 XOR swizzle: LDS row = 128B = 8 x 16B segs; seg_phys = seg_log ^ (row&7).
// gld16 dest linear (t*16B); global SOURCE pre-swizzled; ds_read addr swizzled.
__global__ __launch_bounds__(512) void k_gemm(const u16* __restrict__ A, const u16* __restrict__ Wc,
                                              const float* __restrict__ bias, u16* __restrict__ Call,
                                              u16* __restrict__ vt) {
    __shared__ __align__(16) u16 smem[73728];   // 144 KB
    const int t = threadIdx.x;
    const int lane = t & 63;
    const int wave = t >> 6;
    const int wr = wave & 3;          // M quadrant (64 rows)
    const int wc = wave >> 2;         // N half (64 cols)
    const int q4 = lane >> 4;
    const int lr = lane & 15;

    // bijective XCD-chunk swizzle: 1280 = 8 XCDs x 160; n fastest within a panel
    const int bid = blockIdx.x;
    const int wg = (bid & 7) * 160 + (bid >> 3);
    const int panel = wg / 5;
    const int n = wg - panel * 5;
    const int r0 = panel * 256;
    const int n0 = n * 128;

    // staging: thread t covers (row = t>>3 within 64-row round, seg_phys = t&7)
    const int srow = t >> 3;
    const int slog = (t & 7) ^ (srow & 7);         // inverse-swizzled source segment
    const u16* gA = A  + (size_t)(r0 + srow) * C_ + slog * 8;
    const u16* gB = Wc + (size_t)(n0 + srow) * C_ + slog * 8;

#define STAGE(KT) do {                                        \
        u16* Ab_ = smem + ((KT) % 3) * 24576;                 \
        u16* Bb_ = Ab_ + 16384;                               \
        const int k0_ = (KT) * 64;                            \
        gld16(gA + k0_,             Ab_ + t * 8);             \
        gld16(gA + k0_ +  64 * C_,  Ab_ + 4096  + t * 8);     \
        gld16(gA + k0_ + 128 * C_,  Ab_ + 8192  + t * 8);     \
        gld16(gA + k0_ + 192 * C_,  Ab_ + 12288 + t * 8);     \
        gld16(gB + k0_,             Bb_ + t * 8);             \
        gld16(gB + k0_ +  64 * C_,  Bb_ + 4096  + t * 8);     \
    } while (0)

    f32x4 acc[4][4] = {};
    STAGE(0);
    STAGE(1);

#define KTILE(T, WTN) do {                                                      \
        asm volatile("s_waitcnt vmcnt(" WTN ")" ::: "memory");                  \
        __builtin_amdgcn_s_barrier();                                           \
        if ((T) + 2 < 8) STAGE((T) + 2);                                        \
        const u16* Ab = smem + ((T) % 3) * 24576;                               \
        const u16* Bb = Ab + 16384;                                             \
        s16x8 fa[2][4], fb[2][4];                                               \
        _Pragma("unroll") for (int ks = 0; ks < 2; ++ks) {                      \
            const int sp = ((ks * 4 + q4) ^ (lr & 7)) * 8;                      \
            _Pragma("unroll") for (int mi = 0; mi < 4; ++mi)                    \
                fa[ks][mi] = *(const s16x8*)&Ab[(wr * 64 + mi * 16 + lr) * 64 + sp]; \
            _Pragma("unroll") for (int ni = 0; ni < 4; ++ni)                    \
                fb[ks][ni] = *(const s16x8*)&Bb[(wc * 64 + ni * 16 + lr) * 64 + sp]; \
        }                                                                       \
        __builtin_amdgcn_s_setprio(1);                                          \
        _Pragma("unroll") for (int ks = 0; ks < 2; ++ks)                        \
        _Pragma("unroll") for (int mi = 0; mi < 4; ++mi)                        \
        _Pragma("unroll") for (int ni = 0; ni < 4; ++ni)                        \
            acc[mi][ni] = __builtin_amdgcn_mfma_f32_16x16x32_bf16(fa[ks][mi], fb[ks][ni], acc[mi][ni], 0, 0, 0); \
        __builtin_amdgcn_s_setprio(0);                                          \
    } while (0)

    KTILE(0, "6"); KTILE(1, "6"); KTILE(2, "6"); KTILE(3, "6");
    KTILE(4, "6"); KTILE(5, "6"); KTILE(6, "6"); KTILE(7, "0");
#undef KTILE
#undef STAGE

    if (n == 0) {
        // Q/K: Call[row][o], rows r0..r0+255, o = 0..127
#pragma unroll
        for (int ni = 0; ni < 4; ++ni) {
            const int o = wc * 64 + ni * 16 + lr;
            const float bz = bias[o];
#pragma unroll
            for (int mi = 0; mi < 4; ++mi)
#pragma unroll
                for (int j = 0; j < 4; ++j) {
                    const int rg = r0 + wr * 64 + mi * 16 + q4 * 4 + j;
                    Call[(size_t)rg * 128 + o] = f2bf(acc[mi][ni][j] + bz);
                }
        }
    } else {
        // V: two-pass transpose through T[64][264] (fits in ring slot 0; slot 0's last
        // reader was tile 6, drained before barrier(7)); vt[(bw*512 + cg)*128 + h]
        u16* T = smem;
        const int bw0 = panel * 2;
#pragma unroll
        for (int P = 0; P < 2; ++P) {
            if (wc == P) {
#pragma unroll
                for (int ni = 0; ni < 4; ++ni) {
                    const int c_loc = ni * 16 + lr;                 // 0..63
                    const float bz = bias[n0 + P * 64 + c_loc];
#pragma unroll
                    for (int mi = 0; mi < 4; ++mi) {
                        ushort4 u4;
                        u4.x = f2bf(acc[mi][ni][0] + bz);
                        u4.y = f2bf(acc[mi][ni][1] + bz);
                        u4.z = f2bf(acc[mi][ni][2] + bz);
                        u4.w = f2bf(acc[mi][ni][3] + bz);
                        *(ushort4*)&T[c_loc * 264 + wr * 64 + mi * 16 + q4 * 4] = u4;
                    }
                }
            }
            __syncthreads();
            {
                const int c_loc = t >> 3, hseg = t & 7;
                const int cg = (n - 1) * 128 + P * 64 + c_loc;      // V channel 0..511
#pragma unroll
                for (int k = 0; k < 4; ++k) {
                    const int lh = hseg * 32 + k * 8;               // 0..255
                    const int bw = bw0 + (lh >> 7);
                    const int h  = lh & 127;
                    s16x8 v = *(const s16x8*)&T[c_loc * 264 + lh];
                    *(s16x8*)&vt[((size_t)bw * 512 + cg) * 128 + h] = v;
                }
            }
            __syncthreads();
        }
    }
}

// ------------------------------------------------- K4: per-(b,w) axial attention
__global__ __launch_bounds__(256) void k_attn(const u16* __restrict__ Call, const u16* __restrict__ vt,
                                              u16* __restrict__ outws) {
    __shared__ __align__(16) float E[128][132];
    __shared__ float Rinv[128];
    const int bw = blockIdx.x;
    const int t = threadIdx.x;
    const int lane = t & 63;
    const int wr = t >> 7;
    const int wc = (t >> 6) & 1;
    const int lr = lane & 15, lk = (lane >> 4) * 8;
    const size_t rowbase = (size_t)bw * 128;

    // ---- energy = Q K^T  (K-dim = 64 channels); Call stride 128
    f32x4 e[4][4] = {};
#pragma unroll
    for (int kk = 0; kk < 2; ++kk) {
        s16x8 fq[4], fk[4];
#pragma unroll
        for (int mi = 0; mi < 4; ++mi)
            fq[mi] = *(const s16x8*)&Call[(rowbase + wr * 64 + mi * 16 + lr) * 128 + kk * 32 + lk];
#pragma unroll
        for (int ni = 0; ni < 4; ++ni)
            fk[ni] = *(const s16x8*)&Call[(rowbase + wc * 64 + ni * 16 + lr) * 128 + 64 + kk * 32 + lk];
#pragma unroll
        for (int mi = 0; mi < 4; ++mi)
#pragma unroll
            for (int ni = 0; ni < 4; ++ni)
                e[mi][ni] = __builtin_amdgcn_mfma_f32_16x16x32_bf16(fq[mi], fk[ni], e[mi][ni], 0, 0, 0);
    }
#pragma unroll
    for (int mi = 0; mi < 4; ++mi)
#pragma unroll
        for (int ni = 0; ni < 4; ++ni)
#pragma unroll
            for (int j = 0; j < 4; ++j)
                E[wr * 64 + mi * 16 + (lane >> 4) * 4 + j][wc * 64 + ni * 16 + lr] = e[mi][ni][j];
    __syncthreads();

    // ---- softmax over g (rows h), exp in place, 2 threads per row
    {
        const int h = t >> 1, hf = (t & 1) * 64;
        float m = -1e30f;
        for (int i = 0; i < 64; ++i) m = fmaxf(m, E[h][hf + i]);
        m = fmaxf(m, __shfl_xor(m, 1));
        float s = 0.f;
        for (int i = 0; i < 64; ++i) {
            float p = __expf(E[h][hf + i] - m);
            E[h][hf + i] = p;
            s += p;
        }
        s += __shfl_xor(s, 1);
        if ((t & 1) == 0) Rinv[h] = 1.0f / s;
    }
    __syncthreads();

    float rv[4][4];
#pragma unroll
    for (int mi = 0; mi < 4; ++mi)
#pragma unroll
        for (int j = 0; j < 4; ++j)
            rv[mi][j] = Rinv[wr * 64 + mi * 16 + (lane >> 4) * 4 + j];

    // ---- P rows -> bf16 fragments ONCE
    s16x8 pa[4][4];
#pragma unroll
    for (int kk = 0; kk < 4; ++kk)
#pragma unroll
        for (int mi = 0; mi < 4; ++mi) {
            const float* ep = &E[wr * 64 + mi * 16 + lr][kk * 32 + lk];
            float4 v0 = *(const float4*)ep;
            float4 v1 = *(const float4*)(ep + 4);
            s16x8 a;
            a[0] = (short)f2bf(v0.x); a[1] = (short)f2bf(v0.y);
            a[2] = (short)f2bf(v0.z); a[3] = (short)f2bf(v0.w);
            a[4] = (short)f2bf(v1.x); a[5] = (short)f2bf(v1.y);
            a[6] = (short)f2bf(v1.z); a[7] = (short)f2bf(v1.w);
            pa[kk][mi] = a;
        }

    // ---- out = P V
    for (int cc = 0; cc < 4; ++cc) {
        f32x4 acc[4][4] = {};
#pragma unroll
        for (int kk = 0; kk < 4; ++kk) {
            s16x8 fb[4];
#pragma unroll
            for (int ni = 0; ni < 4; ++ni)
                fb[ni] = *(const s16x8*)&vt[((size_t)bw * 512 + cc * 128 + wc * 64 + ni * 16 + lr) * 128 + kk * 32 + lk];
#pragma unroll
            for (int mi = 0; mi < 4; ++mi)
#pragma unroll
                for (int ni = 0; ni < 4; ++ni)
                    acc[mi][ni] = __builtin_amdgcn_mfma_f32_16x16x32_bf16(pa[kk][mi], fb[ni], acc[mi][ni], 0, 0, 0);
        }
#pragma unroll
        for (int ni = 0; ni < 4; ++ni) {
            const int c = cc * 128 + wc * 64 + ni * 16 + lr;
#pragma unroll
            for (int mi = 0; mi < 4; ++mi)
#pragma unroll
                for (int j = 0; j < 4; ++j) {
                    const int hh = wr * 64 + mi * 16 + (lane >> 4) * 4 + j;
                    outws[(rowbase + hh) * 512 + c] = f2bf(acc[mi][ni][j] * rv[mi][j]);
                }
        }
    }
}

// ------------------------------------------------- K5: out = gamma*out_ws^T + x
__global__ __launch_bounds__(256) void k_merge(const u16* __restrict__ outws, const float* __restrict__ x,
                                               const float* __restrict__ gamma, float* __restrict__ out) {
    __shared__ float tile[64][65];
    const int b  = blockIdx.x >> 7;
    const int h  = blockIdx.x & 127;
    const int c0 = (blockIdx.y >> 1) * 64;
    const int w0 = (blockIdx.y & 1) * 64;
    const float g = gamma[0];
    const int t = threadIdx.x, r = t >> 4, seg = t & 15;
#pragma unroll
    for (int rr = 0; rr < 4; ++rr) {
        const int w = rr * 16 + r;
        ushort4 v = *(const ushort4*)(outws + ((size_t)((b * W_ + w0 + w) * H_) + h) * C_ + c0 + seg * 4);
        tile[w][seg * 4 + 0] = bf2f(v.x); tile[w][seg * 4 + 1] = bf2f(v.y);
        tile[w][seg * 4 + 2] = bf2f(v.z); tile[w][seg * 4 + 3] = bf2f(v.w);
    }
    __syncthreads();
#pragma unroll
    for (int rr = 0; rr < 4; ++rr) {
        const int c = rr * 16 + r;
        const size_t base = ((size_t)(b * C_ + c0 + c) * H_ + h) * W_ + w0 + seg * 4;
        float4 xv = *(const float4*)(x + base);
        float4 o;
        o.x = g * tile[seg * 4 + 0][c] + xv.x;
        o.y = g * tile[seg * 4 + 1][c] + xv.y;
        o.z = g * tile[seg * 4 + 2][c] + xv.z;
        o.w = g * tile[seg * 4 + 3][c] + xv.w;
        *(float4*)(out + base) = o;
    }
}

extern "C" void kernel_launch(void* const* d_in, const int* in_sizes, int n_in,
                              void* d_out, int out_size, void* d_ws, size_t ws_size,
                              hipStream_t stream) {
    const float* x     = (const float*)d_in[0];
    const float* Wq    = (const float*)d_in[1];
    const float* bq    = (const float*)d_in[2];
    const float* Wk    = (const float*)d_in[3];
    const float* bk    = (const float*)d_in[4];
    const float* Wv    = (const float*)d_in[5];
    const float* bv    = (const float*)d_in[6];
    const float* gamma = (const float*)d_in[7];

    char* ws = (char*)d_ws;
    u16*   Wcat  = (u16*)ws;                                   //   0.66 MB
    float* bcat  = (float*)(ws + 655360);                      //   2.5 KB
    u16*   xT    = (u16*)(ws + (1u << 20));                    //  67.1 MB  (reused as out_ws)
    u16*   Call  = (u16*)(ws + (1u << 20) + 67108864);         //  16.8 MB  (Q/K only, stride 128)
    u16*   outws = xT;                                         //  xT dead after k_gemm
    u16*   vt    = (u16*)d_out;                                //  first 67 MB of d_out; dead before k_merge writes

    k_convw<<<dim3((NO_ * C_ + 255) / 256), 256, 0, stream>>>(Wq, bq, Wk, bk, Wv, bv, Wcat, bcat);
    k_transpose_x<<<dim3(B_ * H_, 16), 256, 0, stream>>>(x, xT);
    k_gemm<<<dim3(1280), 512, 0, stream>>>(xT, Wcat, bcat, Call, vt);
    k_attn<<<dim3(B_ * W_), 256, 0, stream>>>(Call, vt, outws);
    k_merge<<<dim3(B_ * H_, 16), 256, 0, stream>>>(outws, x, gamma, (float*)d_out);
}